// Round 2
// baseline (230.625 us; speedup 1.0000x reference)
//
#include <hip/hip_runtime.h>

// UIQI on [16,5,512,512] f32, circular 32x32 box filter, scalar mean output.
// Fused single pass:
//   vertical 32-box  = per-thread register sliding window (lane owns 8 cols)
//   horizontal 32-box = in-wave shuffle combine (window spans lanes L-2..L+2)
// 512 cols == 64 lanes * 8, so mod-64 lane wrap == circular col wrap.
// Output row 512 == row 0, col 512 == col 0 -> weighted 512x512 sum.

#define HH 512
#define WW 512
#define NPLANES 80              // B*C = 16*5
#define BH 16                   // output rows per wave (1 wave per block)
#define BANDS (HH/BH)           // 32 bands per plane
#define NBLOCKS (NPLANES*BANDS) // 2560 -> exactly 10 waves/CU
#define EPSF 1e-8f
#define INV_K (1.0f/1024.0f)

__device__ __forceinline__ void load8(const float* __restrict__ p, float a[8]) {
    const float4* v = reinterpret_cast<const float4*>(p);
    float4 x = v[0], y = v[1];
    a[0]=x.x; a[1]=x.y; a[2]=x.z; a[3]=x.w;
    a[4]=y.x; a[5]=y.y; a[6]=y.z; a[7]=y.w;
}

// Horizontal circular 32-window sums of a row distributed 8 cols/lane.
// Window for col j=8L+k: suffix(k) of lane L-2, full lanes L-1,L,L+1,
// prefix(k) of lane L+2. (k=0: lanes L-2..L+1 fully.)  16 shuffles.
__device__ __forceinline__ void hwin(const float V[8], int lane, float Wo[8]) {
    float pz[8];
    pz[0] = V[0];
#pragma unroll
    for (int k = 1; k < 8; ++k) pz[k] = pz[k-1] + V[k];
    float t = pz[7];
    float u    = t + __shfl(t, (lane+1)&63);    // t_L + t_{L+1}
    float base = u + __shfl(u, (lane+62)&63);   // + t_{L-2} + t_{L-1}
    float pm2[7], pp2[7];
#pragma unroll
    for (int k = 0; k < 7; ++k) pm2[k] = __shfl(pz[k], (lane+62)&63);
#pragma unroll
    for (int k = 0; k < 7; ++k) pp2[k] = __shfl(pz[k], (lane+ 2)&63);
    Wo[0] = base;
#pragma unroll
    for (int k = 1; k < 8; ++k) Wo[k] = base - pm2[k-1] + pp2[k-1];
}

__global__ __launch_bounds__(64)
void uiqi_main(const float* __restrict__ img1, const float* __restrict__ img2,
               double* __restrict__ partial)
{
    const int lane = threadIdx.x;
    const int bid  = blockIdx.x;

    // XCD-aware swizzle: round-robin dispatch -> bid%8 is the XCD. Keep all
    // 32 bands of a plane on one XCD so the 2MB plane pair stays L2-resident.
    const int xcd   = bid & 7;
    const int slot  = bid >> 3;            // 0..319
    const int band  = slot & 31;           // band within plane
    const int plane = xcd + 8*(slot >> 5); // 10 planes per XCD
    const int row0  = band*BH;
    const int j0    = lane*8;

    const float* p1 = img1 + (size_t)plane*HH*WW;
    const float* p2 = img2 + (size_t)plane*HH*WW;

    float V1[8], V2[8], V12[8];
#pragma unroll
    for (int k = 0; k < 8; ++k) { V1[k]=0.f; V2[k]=0.f; V12[k]=0.f; }

    // init vertical window: rows row0-16 .. row0+15 (circular)
#pragma unroll 4
    for (int r = row0-16; r < row0+16; ++r) {
        int rm = r & (HH-1);
        float a[8], b[8];
        load8(p1 + rm*WW + j0, a);
        load8(p2 + rm*WW + j0, b);
#pragma unroll
        for (int k = 0; k < 8; ++k) {
            V1[k]  += a[k];
            V2[k]  += b[k];
            V12[k] += a[k]*b[k];
        }
    }

    double acc = 0.0;
    float na[8], nb[8], nc[8], nd[8];

    for (int i = row0; i < row0 + BH; ++i) {
        const bool more = (i != row0 + BH - 1);
        if (more) {                       // issue next-row loads EARLY
            int radd = (i+16) & (HH-1);
            int rsub = (i-16) & (HH-1);
            load8(p1 + radd*WW + j0, na);
            load8(p2 + radd*WW + j0, nb);
            load8(p1 + rsub*WW + j0, nc);
            load8(p2 + rsub*WW + j0, nd);
        }

        float W1[8], W2[8], W12[8];
        hwin(V1,  lane, W1);
        hwin(V2,  lane, W2);
        hwin(V12, lane, W12);

        float rowsum = 0.f;
        float q0save = 0.f;
#pragma unroll
        for (int k = 0; k < 8; ++k) {
            float mu1  = W1[k]*INV_K, mu2 = W2[k]*INV_K, mu12 = W12[k]*INV_K;
            float m11  = mu1*mu1, m22 = mu2*mu2, m12 = mu1*mu2;
            float s    = (mu1 - m11) + (mu2 - m22);
            float m    = m11 + m22;
            float sig  = mu12 - m12;
            bool  sg = s > EPSF, mg = m > EPSF, sl = s < EPSF, ml = m < EPSF;
            float num = 1.0f, den = 1.0f;
            if (sl && mg) { num = 2.0f*m12;     den = m;   }
            if (sg && ml) { num = 2.0f*sig;     den = s;   }
            if (sg && mg) { num = 4.0f*m12*sig; den = m*s; }
            float q = num * __builtin_amdgcn_rcpf(den);   // 1-ulp rcp
            rowsum += q;
            if (k == 0) q0save = q;
        }
        if (lane == 0) rowsum += q0save;          // col 0 has weight 2
        float wrow = (i == 0) ? 2.0f : 1.0f;      // row 0 has weight 2
        acc += (double)rowsum * (double)wrow;

        if (more) {                               // apply sliding-window update
#pragma unroll
            for (int k = 0; k < 8; ++k) {
                V1[k]  += na[k] - nc[k];
                V2[k]  += nb[k] - nd[k];
                V12[k] += na[k]*nb[k] - nc[k]*nd[k];
            }
        }
    }

    // wave-level double reduction, no LDS
#pragma unroll
    for (int s = 32; s > 0; s >>= 1) acc += __shfl_down(acc, s);
    if (lane == 0) partial[bid] = acc;
}

__global__ __launch_bounds__(256)
void uiqi_finalize(const double* __restrict__ partial, float* __restrict__ out)
{
    __shared__ double sred[256];
    double a = 0.0;
    for (int i = threadIdx.x; i < NBLOCKS; i += 256) a += partial[i];
    sred[threadIdx.x] = a;
    __syncthreads();
    for (int s = 128; s > 0; s >>= 1) {
        if (threadIdx.x < s) sred[threadIdx.x] += sred[threadIdx.x+s];
        __syncthreads();
    }
    // mean over [B,C,513,513] = 80 * 513 * 513 = 21,053,520
    if (threadIdx.x == 0) out[0] = (float)(sred[0] / 21053520.0);
}

extern "C" void kernel_launch(void* const* d_in, const int* in_sizes, int n_in,
                              void* d_out, int out_size, void* d_ws, size_t ws_size,
                              hipStream_t stream)
{
    const float* img1 = (const float*)d_in[0];
    const float* img2 = (const float*)d_in[1];
    // d_in[2] is the frozen box kernel (all 1/1024) — folded into INV_K.
    double* partial = (double*)d_ws;      // 2560 doubles, all written each call
    uiqi_main<<<NBLOCKS, 64, 0, stream>>>(img1, img2, partial);
    uiqi_finalize<<<1, 256, 0, stream>>>(partial, (float*)d_out);
}